// Round 16
// baseline (227.248 us; speedup 1.0000x reference)
//
#include <hip/hip_runtime.h>
#include <math.h>

constexpr int B = 4, T = 2048, C = 1024, H = 16, D = 64;
constexpr int M = B * T;
constexpr size_t BTC = (size_t)B * T * C;
constexpr float QSCALE = 0.18033688011112042f;   // 0.125 * log2(e)
constexpr float ROPE_C = -0.415241011861f;       // -log2(10000)/32

typedef short bf16x8 __attribute__((ext_vector_type(8)));
typedef float f32x4 __attribute__((ext_vector_type(4)));

__device__ inline ushort f2bf(float f) {         // RNE, proven across rounds
  union { float f; unsigned u; } cv; cv.f = f;
  unsigned u = cv.u;
  u += 0x7fffu + ((u >> 16) & 1u);
  return (ushort)(u >> 16);
}
__device__ inline ushort f2bfr(float f) {  // fast round (P only)
  union { float f; unsigned u; } cv; cv.f = f;
  return (ushort)((cv.u + 0x8000u) >> 16);
}

__device__ inline void async_load16(const void* g, void* l) {
  __builtin_amdgcn_global_load_lds(
      (const __attribute__((address_space(1))) void*)g,
      (__attribute__((address_space(3))) void*)l, 16, 0, 0);
}

__device__ __forceinline__ bf16x8 ones_frag() {
  bf16x8 v;
#pragma unroll
  for (int i = 0; i < 8; i++) v[i] = (short)0x3F80;  // bf16 1.0
  return v;
}

// ---------------------------------------------------------------------------
// Merged fp32 -> bf16 conversion: x (B,T,C) then 4 weight matrices (C*C).
// ---------------------------------------------------------------------------
__global__ __launch_bounds__(256) void conv_all(
    const float* __restrict__ x, const float* __restrict__ w0,
    const float* __restrict__ w1, const float* __restrict__ w2,
    const float* __restrict__ w3, ushort* __restrict__ xb,
    ushort* __restrict__ wb) {
  const int XBLK = (int)(BTC / 1024);        // 8192
  const int WBLK = (C * C) / 1024;           // 1024
  int blk = blockIdx.x;
  const float* src;
  ushort* dst;
  int i;
  if (blk < XBLK) {
    src = x; dst = xb;
    i = (blk * 256 + threadIdx.x) * 4;
  } else {
    int wseg = (blk - XBLK) >> 10;           // /WBLK (1024)
    int wblk = (blk - XBLK) & (WBLK - 1);
    src = (wseg == 0) ? w0 : (wseg == 1) ? w1 : (wseg == 2) ? w2 : w3;
    dst = wb + (size_t)wseg * C * C;
    i = (wblk * 256 + threadIdx.x) * 4;
  }
  float4 v = *(const float4*)(src + i);
  ushort4 o;
  o.x = f2bf(v.x); o.y = f2bf(v.y); o.z = f2bf(v.z); o.w = f2bf(v.w);
  *(ushort4*)(dst + i) = o;
}

// ---------------------------------------------------------------------------
// Pipelined GEMM: 128x128 tile, BK=64, 256 thr = 4 waves (2M x 2N), per-wave
// 64x64 output. ONE barrier per K-tile; counted s_waitcnt vmcnt(4) keeps
// B(t+2)'s 4 loads in flight across the barrier. A dbuf + B tri-buf = 80 KiB.
//
// WSTAT selects within-XCD block order (both harness-verified):
//  WSTAT=0 (r14): row-major. Best for qkv (64.7 us): blocks spread across
//    cols -> independent B-miss streams overlap. (r15 col-major on qkv:
//    FETCH 85->49 MB but +6 us — lockstep blocks serialize on shared L2
//    misses. Traffic is not the qkv limiter; latency overlap is.)
//  WSTAT=1 (r15): W-stationary col-major. Best for proj (~ -7 us): at
//    N=1024/NCT=8 the full 2 MB W + 2 MB A-panel set = 4 MB = exactly one
//    XCD L2 -> short latency-bound kernel benefits from residency.
// Established by A/B across rounds 2-15 (do not revisit): BK=32 (r5),
// 8-wave 256-tiles (r1-r3), split QK/V (r9), merged dual-path QKV (r11),
// launch_bounds min-waves>=4 (r13 spill: 4.5x).
// OM=1: fused QKV epilogue (RoPE + V-transpose). OM=0: fp32 out + bias.
// ---------------------------------------------------------------------------
constexpr int QNT = C / 64;  // 16 K-tiles

template <int OM, int NCT, int WSTAT>
__global__ __launch_bounds__(256, 2) void gemm_pipe(
    const ushort* __restrict__ A, const ushort* __restrict__ Wt,
    const float* __restrict__ b0, const float* __restrict__ b1,
    const float* __restrict__ b2, void* __restrict__ out1,
    void* __restrict__ out2, void* __restrict__ out3) {
  __shared__ ushort As[2][128 * 64] __attribute__((aligned(16)));
  __shared__ ushort Bs[3][128 * 64] __attribute__((aligned(16)));
  const int tid = threadIdx.x;
  const int lane = tid & 63;
  const int lrow = lane & 15, quad = lane >> 4;
  const int wave = tid >> 6;
  const int wr = wave >> 1, wc = wave & 1;   // 2M x 2N wave grid
  const int x7 = lrow & 7;

  // XCD-aware bijective swizzle; order per WSTAT (see header).
  int bid = blockIdx.y * NCT + blockIdx.x;
  int row0, col0;
  if (WSTAT == 0) {
    const int cpx = NCT * 8;                 // blocks per XCD
    int lin = (bid & 7) * cpx + (bid >> 3);
    row0 = (lin / NCT) * 128;
    col0 = (lin % NCT) * 128;
  } else {
    int ll = bid >> 3;                       // lin_local
    row0 = ((bid & 7) * 8 + (ll & 7)) * 128;
    col0 = (ll >> 3) * 128;
  }

  // Staging addresses: source col-chunk XOR-swizzled so linear
  // global_load_lds destinations give a swizzled LDS tile.
  unsigned gaA[4], gaB[4];
#pragma unroll
  for (int i = 0; i < 4; i++) {
    int c = tid + i * 256;
    int r = c >> 3, cl = c & 7;
    int g = (cl ^ (r & 7)) * 8;
    gaA[i] = (unsigned)(row0 + r) * C + g;
    gaB[i] = (unsigned)(col0 + r) * C + g;
  }

  f32x4 acc[4][4];
#pragma unroll
  for (int i = 0; i < 4; i++)
#pragma unroll
    for (int j = 0; j < 4; j++) acc[i][j] = (f32x4){0.f, 0.f, 0.f, 0.f};

  // ---- prologue: A(0),B(0),B(1); wait A(0)+B(0), leave B(1) in flight ----
#pragma unroll
  for (int i = 0; i < 4; i++)
    async_load16(A + gaA[i], &As[0][(tid + i * 256) * 8]);
#pragma unroll
  for (int i = 0; i < 4; i++)
    async_load16(Wt + gaB[i], &Bs[0][(tid + i * 256) * 8]);
#pragma unroll
  for (int i = 0; i < 4; i++)
    async_load16(Wt + gaB[i] + 64, &Bs[1][(tid + i * 256) * 8]);
  asm volatile("s_waitcnt vmcnt(4)" ::: "memory");
  __builtin_amdgcn_sched_barrier(0);
  __builtin_amdgcn_s_barrier();

  int bi = 0;  // t % 3
  for (int t = 0; t < QNT; ++t) {
    const int pa = t & 1;
    const ushort* Ap = As[pa];
    const ushort* Bp = Bs[bi];
    int bi2 = bi - 1; if (bi2 < 0) bi2 = 2;  // (bi+2) % 3

    // ---- half 0 (kh=0): reads + A(t+1) prefetch + MFMA, no barrier ----
    {
      const int slot = (quad ^ x7) * 8;
      bf16x8 aF[4], bF[4];
#pragma unroll
      for (int i = 0; i < 4; i++)
        aF[i] = *(const bf16x8*)&Ap[(wr * 64 + i * 16 + lrow) * 64 + slot];
#pragma unroll
      for (int j = 0; j < 4; j++)
        bF[j] = *(const bf16x8*)&Bp[(wc * 64 + j * 16 + lrow) * 64 + slot];
      if (t + 1 < QNT) {
#pragma unroll
        for (int i = 0; i < 4; i++)
          async_load16(A + gaA[i] + (t + 1) * 64,
                       &As[pa ^ 1][(tid + i * 256) * 8]);
      }
      __builtin_amdgcn_s_setprio(1);
#pragma unroll
      for (int i = 0; i < 4; i++)
#pragma unroll
        for (int j = 0; j < 4; j++)
          acc[i][j] = __builtin_amdgcn_mfma_f32_16x16x32_bf16(
              aF[i], bF[j], acc[i][j], 0, 0, 0);
      __builtin_amdgcn_s_setprio(0);
    }

    // ---- half 1 (kh=1): reads + B(t+2) prefetch + MFMA ----
    {
      const int slot = ((4 + quad) ^ x7) * 8;
      bf16x8 aF[4], bF[4];
#pragma unroll
      for (int i = 0; i < 4; i++)
        aF[i] = *(const bf16x8*)&Ap[(wr * 64 + i * 16 + lrow) * 64 + slot];
#pragma unroll
      for (int j = 0; j < 4; j++)
        bF[j] = *(const bf16x8*)&Bp[(wc * 64 + j * 16 + lrow) * 64 + slot];
      if (t + 2 < QNT) {
#pragma unroll
        for (int i = 0; i < 4; i++)
          async_load16(Wt + gaB[i] + (t + 2) * 64,
                       &Bs[bi2][(tid + i * 256) * 8]);
      }
      __builtin_amdgcn_s_setprio(1);
#pragma unroll
      for (int i = 0; i < 4; i++)
#pragma unroll
        for (int j = 0; j < 4; j++)
          acc[i][j] = __builtin_amdgcn_mfma_f32_16x16x32_bf16(
              aF[i], bF[j], acc[i][j], 0, 0, 0);
      __builtin_amdgcn_s_setprio(0);
    }

    // ---- single per-tile sync: counted wait, B(t+2) stays in flight ----
    if (t + 2 < QNT) {
      asm volatile("s_waitcnt vmcnt(4)" ::: "memory");
    } else {
      asm volatile("s_waitcnt vmcnt(0)" ::: "memory");
    }
    __builtin_amdgcn_sched_barrier(0);
    __builtin_amdgcn_s_barrier();
    bi = (bi == 2) ? 0 : bi + 1;
  }

  // ---- epilogue (verbatim from the proven 128^2 kernel) ----
  const int nb = col0 + wc * 64;             // head-aligned (64 | nb)
  const int mbase = row0 + wr * 64;
  const float* bias = (col0 < 1024) ? b0 : (col0 < 2048) ? b1 : b2;
  float bn[4];
#pragma unroll
  for (int j = 0; j < 4; j++) bn[j] = bias[(nb & 1023) + j * 16 + lrow];

  if (OM == 0) {
    const int N = C;
    float* outp = (float*)out1;
#pragma unroll
    for (int i = 0; i < 4; i++)
#pragma unroll
      for (int j = 0; j < 4; j++) {
        int n = nb + j * 16 + lrow;
#pragma unroll
        for (int r = 0; r < 4; r++) {
          int m = mbase + i * 16 + quad * 4 + r;
          outp[(size_t)m * N + n] = acc[i][j][r] + bn[j];
        }
      }
  } else {
    int seg = nb >> 10;                      // 0=Q, 1=K, 2=V
    int hh = (nb & 1023) >> 6;               // head index
    if (seg < 2) {
      // RoPE: lane holds d = lrow(+16) and d+32 -> both pair halves local.
      ushort* dst = (seg == 0) ? (ushort*)out1 : (ushort*)out2;
      float scale = (seg == 0) ? QSCALE : 1.0f;
      float a0 = __builtin_amdgcn_exp2f((float)lrow * ROPE_C);
      float a1 = __builtin_amdgcn_exp2f((float)(lrow + 16) * ROPE_C);
#pragma unroll
      for (int i = 0; i < 4; i++) {
#pragma unroll
        for (int r = 0; r < 4; r++) {
          int m = mbase + i * 16 + quad * 4 + r;
          int tt = m & (T - 1), bb = m >> 11;
          float s0, c0, s1, c1;
          __sincosf((float)tt * a0, &s0, &c0);
          __sincosf((float)tt * a1, &s1, &c1);
          float xr0 = acc[i][0][r] + bn[0];
          float xi0 = acc[i][2][r] + bn[2];
          float xr1 = acc[i][1][r] + bn[1];
          float xi1 = acc[i][3][r] + bn[3];
          ushort* pp = dst + ((size_t)(bb * H + hh) * T + tt) * D + lrow;
          pp[0]  = f2bf((xr0 * c0 - xi0 * s0) * scale);
          pp[32] = f2bf((xr0 * s0 + xi0 * c0) * scale);
          pp[16] = f2bf((xr1 * c1 - xi1 * s1) * scale);
          pp[48] = f2bf((xr1 * s1 + xi1 * c1) * scale);
        }
      }
    } else {
      // V: write transposed (B,H,D,T); 4 consecutive t per quad -> ushort4
      ushort* dst = (ushort*)out3;
#pragma unroll
      for (int i = 0; i < 4; i++) {
        int m0 = mbase + i * 16 + quad * 4;
        int t0 = m0 & (T - 1), bb = m0 >> 11;
        size_t base = (size_t)(bb * H + hh) * D * T + t0;
#pragma unroll
        for (int j = 0; j < 4; j++) {
          int d = j * 16 + lrow;
          ushort4 pk;
          pk.x = f2bf(acc[i][j][0] + bn[j]);
          pk.y = f2bf(acc[i][j][1] + bn[j]);
          pk.z = f2bf(acc[i][j][2] + bn[j]);
          pk.w = f2bf(acc[i][j][3] + bn[j]);
          *(ushort4*)(dst + base + (size_t)d * T) = pk;
        }
      }
    }
  }
}

// ---------------------------------------------------------------------------
// MFMA flash attention v4 (r12/r14-measured version, 53.8 us): K,V
// LDS-staged, double-buffered; setprio; batched two-group P;
// __launch_bounds__(256,3) — do NOT raise to 4 (r13: spill, 4.5x).
// ---------------------------------------------------------------------------
__device__ __forceinline__ void stage_kv(
    const ushort* kbh, const ushort* vbh, int s0,
    ushort* Kl, ushort* Vl, int tid) {
#pragma unroll
  for (int i = 0; i < 2; i++) {
    int c = tid + i * 256;
    int r = c >> 3, cc = c & 7;
    int g = (cc ^ (r & 7)) * 8;
    async_load16(kbh + (size_t)(s0 + r) * D + g, Kl + c * 8);
    async_load16(vbh + (size_t)r * T + s0 + g, Vl + c * 8);
  }
}

template <int MODE>
__device__ __forceinline__ void attn_step4(
    int s0, const ushort* KL, const ushort* VL, ushort* P,
    const bf16x8 (&qf)[2][2], int lrow, int quad, int sw0, int sw1,
    int qg0, int qg1, f32x4 (&o)[4][2], f32x4 (&ol)[2]) {
  bf16x8 kf0[4], kf1[4];
#pragma unroll
  for (int kt = 0; kt < 4; kt++) {
    int base = (kt * 16 + lrow) * 64;
    kf0[kt] = *(const bf16x8*)&KL[base + sw0];
    kf1[kt] = *(const bf16x8*)&KL[base + sw1];
  }
  bf16x8 vf0[4], vf1[4];
#pragma unroll
  for (int ds = 0; ds < 4; ds++) {
    int base = (ds * 16 + lrow) * 64;
    vf0[ds] = *(const bf16x8*)&VL[base + sw0];
    vf1[ds] = *(const bf16x8*)&VL[base + sw1];
  }
#pragma unroll
  for (int g = 0; g < 2; g++) {
    if (MODE == 2 && g == 0) continue;
    int qg = g ? qg1 : qg0;
    f32x4 st[4];
    __builtin_amdgcn_s_setprio(1);
#pragma unroll
    for (int kt = 0; kt < 4; kt++) {
      f32x4 z = {0.f, 0.f, 0.f, 0.f};
      st[kt] = __builtin_amdgcn_mfma_f32_16x16x32_bf16(kf0[kt], qf[g][0], z, 0, 0, 0);
      st[kt] = __builtin_amdgcn_mfma_f32_16x16x32_bf16(kf1[kt], qf[g][1], st[kt], 0, 0, 0);
    }
    __builtin_amdgcn_s_setprio(0);
    if ((MODE == 1 && g == 0) || (MODE == 2 && g == 1)) {
#pragma unroll
      for (int kt = 0; kt < 4; kt++)
#pragma unroll
        for (int r = 0; r < 4; r++)
          if (s0 + kt * 16 + quad * 4 + r > qg) st[kt][r] = -1e30f;
    }
#pragma unroll
    for (int kt = 0; kt < 4; kt++) {
      ushort4 pk;
      pk.x = f2bfr(__builtin_amdgcn_exp2f(st[kt][0]));
      pk.y = f2bfr(__builtin_amdgcn_exp2f(st[kt][1]));
      pk.z = f2bfr(__builtin_amdgcn_exp2f(st[kt][2]));
      pk.w = f2bfr(__builtin_amdgcn_exp2f(st[kt][3]));
      *(ushort4*)&P[((2 * kt + (quad >> 1)) * 32 + g * 16 + lrow) * 8 + (quad & 1) * 4] = pk;
    }
  }
  asm volatile("" ::: "memory");
  bf16x8 ones = ones_frag();
#pragma unroll
  for (int g = 0; g < 2; g++) {
    if (MODE == 2 && g == 0) continue;
    bf16x8 pf0 = *(const bf16x8*)&P[(quad * 32 + g * 16 + lrow) * 8];
    bf16x8 pf1 = *(const bf16x8*)&P[((quad + 4) * 32 + g * 16 + lrow) * 8];
    __builtin_amdgcn_s_setprio(1);
    ol[g] = __builtin_amdgcn_mfma_f32_16x16x32_bf16(ones, pf0, ol[g], 0, 0, 0);
    ol[g] = __builtin_amdgcn_mfma_f32_16x16x32_bf16(ones, pf1, ol[g], 0, 0, 0);
#pragma unroll
    for (int ds = 0; ds < 4; ds++) {
      o[ds][g] = __builtin_amdgcn_mfma_f32_16x16x32_bf16(vf0[ds], pf0, o[ds][g], 0, 0, 0);
      o[ds][g] = __builtin_amdgcn_mfma_f32_16x16x32_bf16(vf1[ds], pf1, o[ds][g], 0, 0, 0);
    }
    __builtin_amdgcn_s_setprio(0);
  }
}

__global__ __launch_bounds__(256, 3) void attn_mfma4(
    const ushort* __restrict__ qb_, const ushort* __restrict__ kb_,
    const ushort* __restrict__ vtb_, ushort* __restrict__ y) {
  __shared__ ushort Kl[2][64 * 64] __attribute__((aligned(16)));
  __shared__ ushort Vl[2][64 * 64] __attribute__((aligned(16)));
  __shared__ ushort Pl[4][2048] __attribute__((aligned(16)));
  int tid = threadIdx.x;
  int wave = tid >> 6, lane = tid & 63;
  int lrow = lane & 15, quad = lane >> 4;
  int qbi = 15 - (int)(blockIdx.x >> 6);
  int bh = blockIdx.x & 63;
  int b = bh >> 4, h = bh & 15;
  int Q0 = qbi * 128;
  ushort* P = Pl[wave];
  const ushort* kbh = kb_ + (size_t)bh * T * D;
  const ushort* vbh = vtb_ + (size_t)bh * D * T;

  int qg0 = Q0 + wave * 16 + lrow;
  int qg1 = qg0 + 64;
  bf16x8 qf[2][2];
  {
    const ushort* qp0 = qb_ + ((size_t)bh * T + qg0) * D + quad * 8;
    qf[0][0] = *(const bf16x8*)qp0;
    qf[0][1] = *(const bf16x8*)(qp0 + 32);
    const ushort* qp1 = qb_ + ((size_t)bh * T + qg1) * D + quad * 8;
    qf[1][0] = *(const bf16x8*)qp1;
    qf[1][1] = *(const bf16x8*)(qp1 + 32);
  }
  int r7 = lrow & 7;
  int sw0 = (quad ^ r7) * 8;
  int sw1 = ((quad + 4) ^ r7) * 8;

  f32x4 o[4][2];
#pragma unroll
  for (int ds = 0; ds < 4; ds++)
#pragma unroll
    for (int g = 0; g < 2; g++) o[ds][g] = (f32x4){0.f, 0.f, 0.f, 0.f};
  f32x4 ol[2] = {(f32x4){0.f, 0.f, 0.f, 0.f}, (f32x4){0.f, 0.f, 0.f, 0.f}};

  int trips = 2 * qbi + 2;
  stage_kv(kbh, vbh, 0, Kl[0], Vl[0], tid);
  int it = 0;
  for (; it < trips - 2; ++it) {
    __syncthreads();
    stage_kv(kbh, vbh, (it + 1) * 64, Kl[(it + 1) & 1], Vl[(it + 1) & 1], tid);
    attn_step4<0>(it * 64, Kl[it & 1], Vl[it & 1], P, qf, lrow, quad, sw0, sw1,
                  qg0, qg1, o, ol);
  }
  __syncthreads();
  stage_kv(kbh, vbh, (it + 1) * 64, Kl[(it + 1) & 1], Vl[(it + 1) & 1], tid);
  attn_step4<1>(it * 64, Kl[it & 1], Vl[it & 1], P, qf, lrow, quad, sw0, sw1,
                qg0, qg1, o, ol);
  ++it;
  __syncthreads();
  attn_step4<2>(it * 64, Kl[it & 1], Vl[it & 1], P, qf, lrow, quad, sw0, sw1,
                qg0, qg1, o, ol);

#pragma unroll
  for (int g = 0; g < 2; g++) {
    float inv = 1.f / ol[g][0];
    int qg = g ? qg1 : qg0;
#pragma unroll
    for (int ds = 0; ds < 4; ds++) {
      ushort4 pk;
      pk.x = f2bf(o[ds][g][0] * inv);
      pk.y = f2bf(o[ds][g][1] * inv);
      pk.z = f2bf(o[ds][g][2] * inv);
      pk.w = f2bf(o[ds][g][3] * inv);
      *(ushort4*)(y + ((size_t)b * T + qg) * C + h * D + ds * 16 + quad * 4) = pk;
    }
  }
}

// ---------------------------------------------------------------------------
extern "C" void kernel_launch(void* const* d_in, const int* in_sizes, int n_in,
                              void* d_out, int out_size, void* d_ws, size_t ws_size,
                              hipStream_t stream) {
  const float* x  = (const float*)d_in[0];
  const float* wq = (const float*)d_in[1];
  const float* bq = (const float*)d_in[2];
  const float* wk = (const float*)d_in[3];
  const float* bk = (const float*)d_in[4];
  const float* wv = (const float*)d_in[5];
  const float* bv = (const float*)d_in[6];
  const float* wp = (const float*)d_in[7];
  const float* bp = (const float*)d_in[8];
  float* out = (float*)d_out;

  ushort* xb    = (ushort*)d_ws;            // (B,T,C)   bf16
  ushort* qb    = xb + BTC;                 // (B,H,T,D) bf16 (exp2-scaled)
  ushort* kb    = qb + BTC;                 // (B,H,T,D) bf16
  ushort* vtb   = kb + BTC;                 // (B,H,D,T) bf16
  ushort* yb    = vtb + BTC;                // (B,T,C)   bf16
  ushort* wqkvb = yb + BTC;                 // (3C,C) bf16, wpb after
  ushort* wpb   = wqkvb + (size_t)3 * C * C;

  // merged input+weight bf16 conversion (one launch)
  conv_all<<<(int)(BTC / 1024) + 4 * (C * C) / 1024, 256, 0, stream>>>(
      x, wq, wk, wv, wp, xb, wqkvb);

  // fused QKV GEMM: row-major within-XCD order (r14 best: 64.7 us)
  dim3 qkv_grid(3 * C / 128, M / 128);      // (24, 64)
  gemm_pipe<1, 24, 0><<<qkv_grid, 256, 0, stream>>>(
      xb, wqkvb, bq, bk, bv, qb, kb, vtb);

  attn_mfma4<<<(B * H * T / 128), 256, 0, stream>>>(qb, kb, vtb, yb);

  // proj GEMM: W-stationary within-XCD order (r15 gain: ~-7 us)
  dim3 proj_grid(C / 128, M / 128);         // (8, 64)
  gemm_pipe<0, 8, 1><<<proj_grid, 256, 0, stream>>>(
      yb, wpb, bp, bp, bp, out, nullptr, nullptr);
}

// Round 17
// 222.118 us; speedup vs baseline: 1.0231x; 1.0231x over previous
//
#include <hip/hip_runtime.h>
#include <math.h>

constexpr int B = 4, T = 2048, C = 1024, H = 16, D = 64;
constexpr int M = B * T;
constexpr size_t BTC = (size_t)B * T * C;
constexpr float QSCALE = 0.18033688011112042f;   // 0.125 * log2(e)
constexpr float ROPE_C = -0.415241011861f;       // -log2(10000)/32

typedef short bf16x8 __attribute__((ext_vector_type(8)));
typedef float f32x4 __attribute__((ext_vector_type(4)));

__device__ inline ushort f2bf(float f) {         // RNE, proven across rounds
  union { float f; unsigned u; } cv; cv.f = f;
  unsigned u = cv.u;
  u += 0x7fffu + ((u >> 16) & 1u);
  return (ushort)(u >> 16);
}
__device__ inline ushort f2bfr(float f) {  // fast round (P only)
  union { float f; unsigned u; } cv; cv.f = f;
  return (ushort)((cv.u + 0x8000u) >> 16);
}

__device__ inline void async_load16(const void* g, void* l) {
  __builtin_amdgcn_global_load_lds(
      (const __attribute__((address_space(1))) void*)g,
      (__attribute__((address_space(3))) void*)l, 16, 0, 0);
}

__device__ __forceinline__ bf16x8 ones_frag() {
  bf16x8 v;
#pragma unroll
  for (int i = 0; i < 8; i++) v[i] = (short)0x3F80;  // bf16 1.0
  return v;
}

// ---------------------------------------------------------------------------
// Merged fp32 -> bf16 conversion: x (B,T,C) then 4 weight matrices (C*C).
// ---------------------------------------------------------------------------
__global__ __launch_bounds__(256) void conv_all(
    const float* __restrict__ x, const float* __restrict__ w0,
    const float* __restrict__ w1, const float* __restrict__ w2,
    const float* __restrict__ w3, ushort* __restrict__ xb,
    ushort* __restrict__ wb) {
  const int XBLK = (int)(BTC / 1024);        // 8192
  const int WBLK = (C * C) / 1024;           // 1024
  int blk = blockIdx.x;
  const float* src;
  ushort* dst;
  int i;
  if (blk < XBLK) {
    src = x; dst = xb;
    i = (blk * 256 + threadIdx.x) * 4;
  } else {
    int wseg = (blk - XBLK) >> 10;           // /WBLK (1024)
    int wblk = (blk - XBLK) & (WBLK - 1);
    src = (wseg == 0) ? w0 : (wseg == 1) ? w1 : (wseg == 2) ? w2 : w3;
    dst = wb + (size_t)wseg * C * C;
    i = (wblk * 256 + threadIdx.x) * 4;
  }
  float4 v = *(const float4*)(src + i);
  ushort4 o;
  o.x = f2bf(v.x); o.y = f2bf(v.y); o.z = f2bf(v.z); o.w = f2bf(v.w);
  *(ushort4*)(dst + i) = o;
}

// ---------------------------------------------------------------------------
// Pipelined GEMM (SESSION-BEST configuration, 223.1 us total):
// 128x128 tile, BK=64, 256 thr = 4 waves (2M x 2N), per-wave 64x64 output.
// ONE barrier per K-tile; counted s_waitcnt vmcnt(4) keeps B(t+2)'s 4 loads
// in flight across the barrier. A dbuf 32 KiB + B tri-buf 48 KiB = 80 KiB.
// Within-XCD block order: W-stationary col-major (r15-measured best total).
// NOTE (r14/r15/r16): per-kernel times for this binary vary +-7 us with
// machine/cache state; total band 223-227 us. Hybrid per-kernel orderings
// (r16) did not beat this uniform config.
// Established by A/B across rounds 2-16 (do not revisit): BK=32 (r5),
// 8-wave 256-tiles (r1-r3), split QK/V (r9), merged dual-path QKV (r11),
// launch_bounds min-waves>=4 (r13 spill: 4.5x slowdown).
// OM=1: fused QKV epilogue (RoPE + V-transpose). OM=0: fp32 out + bias.
// ---------------------------------------------------------------------------
constexpr int QNT = C / 64;  // 16 K-tiles

template <int OM, int NCT>
__global__ __launch_bounds__(256, 2) void gemm_pipe(
    const ushort* __restrict__ A, const ushort* __restrict__ Wt,
    const float* __restrict__ b0, const float* __restrict__ b1,
    const float* __restrict__ b2, void* __restrict__ out1,
    void* __restrict__ out2, void* __restrict__ out3) {
  __shared__ ushort As[2][128 * 64] __attribute__((aligned(16)));
  __shared__ ushort Bs[3][128 * 64] __attribute__((aligned(16)));
  const int tid = threadIdx.x;
  const int lane = tid & 63;
  const int lrow = lane & 15, quad = lane >> 4;
  const int wave = tid >> 6;
  const int wr = wave >> 1, wc = wave & 1;   // 2M x 2N wave grid
  const int x7 = lrow & 7;

  // XCD-aware bijective swizzle, W-stationary within each XCD:
  // XCD x gets lin_local in [0, NCT*8); col = lin_local/8 (slow),
  // row-panel = x*8 + lin_local%8 (fast).
  int bid = blockIdx.y * NCT + blockIdx.x;
  int ll = bid >> 3;                         // lin_local
  int row0 = ((bid & 7) * 8 + (ll & 7)) * 128;
  int col0 = (ll >> 3) * 128;

  // Staging addresses: source col-chunk XOR-swizzled so linear
  // global_load_lds destinations give a swizzled LDS tile.
  unsigned gaA[4], gaB[4];
#pragma unroll
  for (int i = 0; i < 4; i++) {
    int c = tid + i * 256;
    int r = c >> 3, cl = c & 7;
    int g = (cl ^ (r & 7)) * 8;
    gaA[i] = (unsigned)(row0 + r) * C + g;
    gaB[i] = (unsigned)(col0 + r) * C + g;
  }

  f32x4 acc[4][4];
#pragma unroll
  for (int i = 0; i < 4; i++)
#pragma unroll
    for (int j = 0; j < 4; j++) acc[i][j] = (f32x4){0.f, 0.f, 0.f, 0.f};

  // ---- prologue: A(0),B(0),B(1); wait A(0)+B(0), leave B(1) in flight ----
#pragma unroll
  for (int i = 0; i < 4; i++)
    async_load16(A + gaA[i], &As[0][(tid + i * 256) * 8]);
#pragma unroll
  for (int i = 0; i < 4; i++)
    async_load16(Wt + gaB[i], &Bs[0][(tid + i * 256) * 8]);
#pragma unroll
  for (int i = 0; i < 4; i++)
    async_load16(Wt + gaB[i] + 64, &Bs[1][(tid + i * 256) * 8]);
  asm volatile("s_waitcnt vmcnt(4)" ::: "memory");
  __builtin_amdgcn_sched_barrier(0);
  __builtin_amdgcn_s_barrier();

  int bi = 0;  // t % 3
  for (int t = 0; t < QNT; ++t) {
    const int pa = t & 1;
    const ushort* Ap = As[pa];
    const ushort* Bp = Bs[bi];
    int bi2 = bi - 1; if (bi2 < 0) bi2 = 2;  // (bi+2) % 3

    // ---- half 0 (kh=0): reads + A(t+1) prefetch + MFMA, no barrier ----
    {
      const int slot = (quad ^ x7) * 8;
      bf16x8 aF[4], bF[4];
#pragma unroll
      for (int i = 0; i < 4; i++)
        aF[i] = *(const bf16x8*)&Ap[(wr * 64 + i * 16 + lrow) * 64 + slot];
#pragma unroll
      for (int j = 0; j < 4; j++)
        bF[j] = *(const bf16x8*)&Bp[(wc * 64 + j * 16 + lrow) * 64 + slot];
      if (t + 1 < QNT) {
#pragma unroll
        for (int i = 0; i < 4; i++)
          async_load16(A + gaA[i] + (t + 1) * 64,
                       &As[pa ^ 1][(tid + i * 256) * 8]);
      }
      __builtin_amdgcn_s_setprio(1);
#pragma unroll
      for (int i = 0; i < 4; i++)
#pragma unroll
        for (int j = 0; j < 4; j++)
          acc[i][j] = __builtin_amdgcn_mfma_f32_16x16x32_bf16(
              aF[i], bF[j], acc[i][j], 0, 0, 0);
      __builtin_amdgcn_s_setprio(0);
    }

    // ---- half 1 (kh=1): reads + B(t+2) prefetch + MFMA ----
    {
      const int slot = ((4 + quad) ^ x7) * 8;
      bf16x8 aF[4], bF[4];
#pragma unroll
      for (int i = 0; i < 4; i++)
        aF[i] = *(const bf16x8*)&Ap[(wr * 64 + i * 16 + lrow) * 64 + slot];
#pragma unroll
      for (int j = 0; j < 4; j++)
        bF[j] = *(const bf16x8*)&Bp[(wc * 64 + j * 16 + lrow) * 64 + slot];
      if (t + 2 < QNT) {
#pragma unroll
        for (int i = 0; i < 4; i++)
          async_load16(Wt + gaB[i] + (t + 2) * 64,
                       &Bs[bi2][(tid + i * 256) * 8]);
      }
      __builtin_amdgcn_s_setprio(1);
#pragma unroll
      for (int i = 0; i < 4; i++)
#pragma unroll
        for (int j = 0; j < 4; j++)
          acc[i][j] = __builtin_amdgcn_mfma_f32_16x16x32_bf16(
              aF[i], bF[j], acc[i][j], 0, 0, 0);
      __builtin_amdgcn_s_setprio(0);
    }

    // ---- single per-tile sync: counted wait, B(t+2) stays in flight ----
    if (t + 2 < QNT) {
      asm volatile("s_waitcnt vmcnt(4)" ::: "memory");
    } else {
      asm volatile("s_waitcnt vmcnt(0)" ::: "memory");
    }
    __builtin_amdgcn_sched_barrier(0);
    __builtin_amdgcn_s_barrier();
    bi = (bi == 2) ? 0 : bi + 1;
  }

  // ---- epilogue (verbatim from the proven 128^2 kernel) ----
  const int nb = col0 + wc * 64;             // head-aligned (64 | nb)
  const int mbase = row0 + wr * 64;
  const float* bias = (col0 < 1024) ? b0 : (col0 < 2048) ? b1 : b2;
  float bn[4];
#pragma unroll
  for (int j = 0; j < 4; j++) bn[j] = bias[(nb & 1023) + j * 16 + lrow];

  if (OM == 0) {
    const int N = C;
    float* outp = (float*)out1;
#pragma unroll
    for (int i = 0; i < 4; i++)
#pragma unroll
      for (int j = 0; j < 4; j++) {
        int n = nb + j * 16 + lrow;
#pragma unroll
        for (int r = 0; r < 4; r++) {
          int m = mbase + i * 16 + quad * 4 + r;
          outp[(size_t)m * N + n] = acc[i][j][r] + bn[j];
        }
      }
  } else {
    int seg = nb >> 10;                      // 0=Q, 1=K, 2=V
    int hh = (nb & 1023) >> 6;               // head index
    if (seg < 2) {
      // RoPE: lane holds d = lrow(+16) and d+32 -> both pair halves local.
      ushort* dst = (seg == 0) ? (ushort*)out1 : (ushort*)out2;
      float scale = (seg == 0) ? QSCALE : 1.0f;
      float a0 = __builtin_amdgcn_exp2f((float)lrow * ROPE_C);
      float a1 = __builtin_amdgcn_exp2f((float)(lrow + 16) * ROPE_C);
#pragma unroll
      for (int i = 0; i < 4; i++) {
#pragma unroll
        for (int r = 0; r < 4; r++) {
          int m = mbase + i * 16 + quad * 4 + r;
          int tt = m & (T - 1), bb = m >> 11;
          float s0, c0, s1, c1;
          __sincosf((float)tt * a0, &s0, &c0);
          __sincosf((float)tt * a1, &s1, &c1);
          float xr0 = acc[i][0][r] + bn[0];
          float xi0 = acc[i][2][r] + bn[2];
          float xr1 = acc[i][1][r] + bn[1];
          float xi1 = acc[i][3][r] + bn[3];
          ushort* pp = dst + ((size_t)(bb * H + hh) * T + tt) * D + lrow;
          pp[0]  = f2bf((xr0 * c0 - xi0 * s0) * scale);
          pp[32] = f2bf((xr0 * s0 + xi0 * c0) * scale);
          pp[16] = f2bf((xr1 * c1 - xi1 * s1) * scale);
          pp[48] = f2bf((xr1 * s1 + xi1 * c1) * scale);
        }
      }
    } else {
      // V: write transposed (B,H,D,T); 4 consecutive t per quad -> ushort4
      ushort* dst = (ushort*)out3;
#pragma unroll
      for (int i = 0; i < 4; i++) {
        int m0 = mbase + i * 16 + quad * 4;
        int t0 = m0 & (T - 1), bb = m0 >> 11;
        size_t base = (size_t)(bb * H + hh) * D * T + t0;
#pragma unroll
        for (int j = 0; j < 4; j++) {
          int d = j * 16 + lrow;
          ushort4 pk;
          pk.x = f2bf(acc[i][j][0] + bn[j]);
          pk.y = f2bf(acc[i][j][1] + bn[j]);
          pk.z = f2bf(acc[i][j][2] + bn[j]);
          pk.w = f2bf(acc[i][j][3] + bn[j]);
          *(ushort4*)(dst + base + (size_t)d * T) = pk;
        }
      }
    }
  }
}

// ---------------------------------------------------------------------------
// MFMA flash attention v4 (r12/r14-measured version, ~54 us): K,V
// LDS-staged, double-buffered; setprio; batched two-group P;
// __launch_bounds__(256,3) — do NOT raise to 4 (r13: spill, 4.5x).
// ---------------------------------------------------------------------------
__device__ __forceinline__ void stage_kv(
    const ushort* kbh, const ushort* vbh, int s0,
    ushort* Kl, ushort* Vl, int tid) {
#pragma unroll
  for (int i = 0; i < 2; i++) {
    int c = tid + i * 256;
    int r = c >> 3, cc = c & 7;
    int g = (cc ^ (r & 7)) * 8;
    async_load16(kbh + (size_t)(s0 + r) * D + g, Kl + c * 8);
    async_load16(vbh + (size_t)r * T + s0 + g, Vl + c * 8);
  }
}

template <int MODE>
__device__ __forceinline__ void attn_step4(
    int s0, const ushort* KL, const ushort* VL, ushort* P,
    const bf16x8 (&qf)[2][2], int lrow, int quad, int sw0, int sw1,
    int qg0, int qg1, f32x4 (&o)[4][2], f32x4 (&ol)[2]) {
  bf16x8 kf0[4], kf1[4];
#pragma unroll
  for (int kt = 0; kt < 4; kt++) {
    int base = (kt * 16 + lrow) * 64;
    kf0[kt] = *(const bf16x8*)&KL[base + sw0];
    kf1[kt] = *(const bf16x8*)&KL[base + sw1];
  }
  bf16x8 vf0[4], vf1[4];
#pragma unroll
  for (int ds = 0; ds < 4; ds++) {
    int base = (ds * 16 + lrow) * 64;
    vf0[ds] = *(const bf16x8*)&VL[base + sw0];
    vf1[ds] = *(const bf16x8*)&VL[base + sw1];
  }
#pragma unroll
  for (int g = 0; g < 2; g++) {
    if (MODE == 2 && g == 0) continue;
    int qg = g ? qg1 : qg0;
    f32x4 st[4];
    __builtin_amdgcn_s_setprio(1);
#pragma unroll
    for (int kt = 0; kt < 4; kt++) {
      f32x4 z = {0.f, 0.f, 0.f, 0.f};
      st[kt] = __builtin_amdgcn_mfma_f32_16x16x32_bf16(kf0[kt], qf[g][0], z, 0, 0, 0);
      st[kt] = __builtin_amdgcn_mfma_f32_16x16x32_bf16(kf1[kt], qf[g][1], st[kt], 0, 0, 0);
    }
    __builtin_amdgcn_s_setprio(0);
    if ((MODE == 1 && g == 0) || (MODE == 2 && g == 1)) {
#pragma unroll
      for (int kt = 0; kt < 4; kt++)
#pragma unroll
        for (int r = 0; r < 4; r++)
          if (s0 + kt * 16 + quad * 4 + r > qg) st[kt][r] = -1e30f;
    }
#pragma unroll
    for (int kt = 0; kt < 4; kt++) {
      ushort4 pk;
      pk.x = f2bfr(__builtin_amdgcn_exp2f(st[kt][0]));
      pk.y = f2bfr(__builtin_amdgcn_exp2f(st[kt][1]));
      pk.z = f2bfr(__builtin_amdgcn_exp2f(st[kt][2]));
      pk.w = f2bfr(__builtin_amdgcn_exp2f(st[kt][3]));
      *(ushort4*)&P[((2 * kt + (quad >> 1)) * 32 + g * 16 + lrow) * 8 + (quad & 1) * 4] = pk;
    }
  }
  asm volatile("" ::: "memory");
  bf16x8 ones = ones_frag();
#pragma unroll
  for (int g = 0; g < 2; g++) {
    if (MODE == 2 && g == 0) continue;
    bf16x8 pf0 = *(const bf16x8*)&P[(quad * 32 + g * 16 + lrow) * 8];
    bf16x8 pf1 = *(const bf16x8*)&P[((quad + 4) * 32 + g * 16 + lrow) * 8];
    __builtin_amdgcn_s_setprio(1);
    ol[g] = __builtin_amdgcn_mfma_f32_16x16x32_bf16(ones, pf0, ol[g], 0, 0, 0);
    ol[g] = __builtin_amdgcn_mfma_f32_16x16x32_bf16(ones, pf1, ol[g], 0, 0, 0);
#pragma unroll
    for (int ds = 0; ds < 4; ds++) {
      o[ds][g] = __builtin_amdgcn_mfma_f32_16x16x32_bf16(vf0[ds], pf0, o[ds][g], 0, 0, 0);
      o[ds][g] = __builtin_amdgcn_mfma_f32_16x16x32_bf16(vf1[ds], pf1, o[ds][g], 0, 0, 0);
    }
    __builtin_amdgcn_s_setprio(0);
  }
}

__global__ __launch_bounds__(256, 3) void attn_mfma4(
    const ushort* __restrict__ qb_, const ushort* __restrict__ kb_,
    const ushort* __restrict__ vtb_, ushort* __restrict__ y) {
  __shared__ ushort Kl[2][64 * 64] __attribute__((aligned(16)));
  __shared__ ushort Vl[2][64 * 64] __attribute__((aligned(16)));
  __shared__ ushort Pl[4][2048] __attribute__((aligned(16)));
  int tid = threadIdx.x;
  int wave = tid >> 6, lane = tid & 63;
  int lrow = lane & 15, quad = lane >> 4;
  int qbi = 15 - (int)(blockIdx.x >> 6);
  int bh = blockIdx.x & 63;
  int b = bh >> 4, h = bh & 15;
  int Q0 = qbi * 128;
  ushort* P = Pl[wave];
  const ushort* kbh = kb_ + (size_t)bh * T * D;
  const ushort* vbh = vtb_ + (size_t)bh * D * T;

  int qg0 = Q0 + wave * 16 + lrow;
  int qg1 = qg0 + 64;
  bf16x8 qf[2][2];
  {
    const ushort* qp0 = qb_ + ((size_t)bh * T + qg0) * D + quad * 8;
    qf[0][0] = *(const bf16x8*)qp0;
    qf[0][1] = *(const bf16x8*)(qp0 + 32);
    const ushort* qp1 = qb_ + ((size_t)bh * T + qg1) * D + quad * 8;
    qf[1][0] = *(const bf16x8*)qp1;
    qf[1][1] = *(const bf16x8*)(qp1 + 32);
  }
  int r7 = lrow & 7;
  int sw0 = (quad ^ r7) * 8;
  int sw1 = ((quad + 4) ^ r7) * 8;

  f32x4 o[4][2];
#pragma unroll
  for (int ds = 0; ds < 4; ds++)
#pragma unroll
    for (int g = 0; g < 2; g++) o[ds][g] = (f32x4){0.f, 0.f, 0.f, 0.f};
  f32x4 ol[2] = {(f32x4){0.f, 0.f, 0.f, 0.f}, (f32x4){0.f, 0.f, 0.f, 0.f}};

  int trips = 2 * qbi + 2;
  stage_kv(kbh, vbh, 0, Kl[0], Vl[0], tid);
  int it = 0;
  for (; it < trips - 2; ++it) {
    __syncthreads();
    stage_kv(kbh, vbh, (it + 1) * 64, Kl[(it + 1) & 1], Vl[(it + 1) & 1], tid);
    attn_step4<0>(it * 64, Kl[it & 1], Vl[it & 1], P, qf, lrow, quad, sw0, sw1,
                  qg0, qg1, o, ol);
  }
  __syncthreads();
  stage_kv(kbh, vbh, (it + 1) * 64, Kl[(it + 1) & 1], Vl[(it + 1) & 1], tid);
  attn_step4<1>(it * 64, Kl[it & 1], Vl[it & 1], P, qf, lrow, quad, sw0, sw1,
                qg0, qg1, o, ol);
  ++it;
  __syncthreads();
  attn_step4<2>(it * 64, Kl[it & 1], Vl[it & 1], P, qf, lrow, quad, sw0, sw1,
                qg0, qg1, o, ol);

#pragma unroll
  for (int g = 0; g < 2; g++) {
    float inv = 1.f / ol[g][0];
    int qg = g ? qg1 : qg0;
#pragma unroll
    for (int ds = 0; ds < 4; ds++) {
      ushort4 pk;
      pk.x = f2bf(o[ds][g][0] * inv);
      pk.y = f2bf(o[ds][g][1] * inv);
      pk.z = f2bf(o[ds][g][2] * inv);
      pk.w = f2bf(o[ds][g][3] * inv);
      *(ushort4*)(y + ((size_t)b * T + qg) * C + h * D + ds * 16 + quad * 4) = pk;
    }
  }
}

// ---------------------------------------------------------------------------
extern "C" void kernel_launch(void* const* d_in, const int* in_sizes, int n_in,
                              void* d_out, int out_size, void* d_ws, size_t ws_size,
                              hipStream_t stream) {
  const float* x  = (const float*)d_in[0];
  const float* wq = (const float*)d_in[1];
  const float* bq = (const float*)d_in[2];
  const float* wk = (const float*)d_in[3];
  const float* bk = (const float*)d_in[4];
  const float* wv = (const float*)d_in[5];
  const float* bv = (const float*)d_in[6];
  const float* wp = (const float*)d_in[7];
  const float* bp = (const float*)d_in[8];
  float* out = (float*)d_out;

  ushort* xb    = (ushort*)d_ws;            // (B,T,C)   bf16
  ushort* qb    = xb + BTC;                 // (B,H,T,D) bf16 (exp2-scaled)
  ushort* kb    = qb + BTC;                 // (B,H,T,D) bf16
  ushort* vtb   = kb + BTC;                 // (B,H,D,T) bf16
  ushort* yb    = vtb + BTC;                // (B,T,C)   bf16
  ushort* wqkvb = yb + BTC;                 // (3C,C) bf16, wpb after
  ushort* wpb   = wqkvb + (size_t)3 * C * C;

  // merged input+weight bf16 conversion (one launch)
  conv_all<<<(int)(BTC / 1024) + 4 * (C * C) / 1024, 256, 0, stream>>>(
      x, wq, wk, wv, wp, xb, wqkvb);

  // fused QKV GEMM: BK=64 pipelined, 2 blocks/CU, 1536 blocks
  dim3 qkv_grid(3 * C / 128, M / 128);      // (24, 64)
  gemm_pipe<1, 24><<<qkv_grid, 256, 0, stream>>>(
      xb, wqkvb, bq, bk, bv, qb, kb, vtb);

  attn_mfma4<<<(B * H * T / 128), 256, 0, stream>>>(qb, kb, vtb, yb);

  // proj GEMM on the same pipeline, 512 blocks (2/CU)
  dim3 proj_grid(C / 128, M / 128);         // (8, 64)
  gemm_pipe<0, 8><<<proj_grid, 256, 0, stream>>>(
      yb, wpb, bp, bp, bp, out, nullptr, nullptr);
}